// Round 1
// baseline (164.361 us; speedup 1.0000x reference)
//
#include <hip/hip_runtime.h>

#define B_ 64
#define L_ 1024
#define M_ 256
#define F_ 256

// One block per l. 256 threads. Each thread owns an 8x8 (b,m) register tile:
//   tx = t&31 -> m = tx + 32*j (j=0..7), ty = t>>5 -> b = ty*8 + i (i=0..7)
// K (=F) tiled by 32. Q tile XOR-swizzled in LDS for conflict-free b128 reads.
__launch_bounds__(256, 2)
__global__ void mq_fused_kernel(const float* __restrict__ patch,
                                const float* __restrict__ queue,
                                float* __restrict__ out) {
    const int l  = blockIdx.x;
    const int t  = threadIdx.x;
    const int tx = t & 31;
    const int ty = t >> 5;

    __shared__ float Pl[64 * 36];     // [b][f] padded stride 36 floats (144B, 16B aligned)
    __shared__ float Ql[256 * 32];    // [m][f] stride 32, chunk index XOR-swizzled by (m&7)
    __shared__ int   sidx[64];

    float acc[8][8];
#pragma unroll
    for (int i = 0; i < 8; ++i)
#pragma unroll
        for (int j = 0; j < 8; ++j) acc[i][j] = 0.f;

    const int lr = t >> 3;   // 0..31: row group for loads
    const int lc = t & 7;    // 0..7 : float4 chunk within 32-float tile row

    for (int ft = 0; ft < 8; ++ft) {
        __syncthreads();
        // P tile: 64 rows x 32 f, 2 float4 per thread, coalesced 128B per row
#pragma unroll
        for (int p = 0; p < 2; ++p) {
            const int row = lr + 32 * p;                       // b
            const float4 v = *reinterpret_cast<const float4*>(
                &patch[((size_t)row * L_ + l) * F_ + ft * 32 + lc * 4]);
            *reinterpret_cast<float4*>(&Pl[row * 36 + lc * 4]) = v;
        }
        // Q tile: 256 rows x 32 f, 8 float4 per thread, XOR-swizzled LDS chunk
#pragma unroll
        for (int p = 0; p < 8; ++p) {
            const int row = lr + 32 * p;                       // m
            const float4 v = *reinterpret_cast<const float4*>(
                &queue[((size_t)l * M_ + row) * F_ + ft * 32 + lc * 4]);
            const int cs = lc ^ (row & 7);
            *reinterpret_cast<float4*>(&Ql[row * 32 + cs * 4]) = v;
        }
        __syncthreads();

#pragma unroll
        for (int f4 = 0; f4 < 8; ++f4) {
            float4 pr[8], qr[8];
#pragma unroll
            for (int i = 0; i < 8; ++i)
                pr[i] = *reinterpret_cast<const float4*>(
                    &Pl[(ty * 8 + i) * 36 + f4 * 4]);
            const int qc = f4 ^ (tx & 7);                      // (tx+32j)&7 == tx&7
#pragma unroll
            for (int j = 0; j < 8; ++j)
                qr[j] = *reinterpret_cast<const float4*>(
                    &Ql[(tx + 32 * j) * 32 + qc * 4]);
#pragma unroll
            for (int i = 0; i < 8; ++i)
#pragma unroll
                for (int j = 0; j < 8; ++j) {
                    acc[i][j] += pr[i].x * qr[j].x;
                    acc[i][j] += pr[i].y * qr[j].y;
                    acc[i][j] += pr[i].z * qr[j].z;
                    acc[i][j] += pr[i].w * qr[j].w;
                }
        }
    }

    // argmax over m per b. Strict '>' keeps the lowest m in-thread (j ascending
    // => m ascending); cross-lane combine prefers lower idx on exact tie
    // (numpy first-occurrence semantics).
#pragma unroll
    for (int i = 0; i < 8; ++i) {
        float bv = acc[i][0];
        int   bi = tx;
#pragma unroll
        for (int j = 1; j < 8; ++j) {
            const float cv = acc[i][j];
            const int   ci = tx + 32 * j;
            if (cv > bv) { bv = cv; bi = ci; }
        }
        // butterfly across the 32 tx-lanes (xor<32 stays within each 32-half)
#pragma unroll
        for (int off = 16; off >= 1; off >>= 1) {
            const float ov = __shfl_xor(bv, off);
            const int   oi = __shfl_xor(bi, off);
            if (ov > bv || (ov == bv && oi < bi)) { bv = ov; bi = oi; }
        }
        if (tx == 0) sidx[ty * 8 + i] = bi;
    }
    __syncthreads();

    // gather: out[b][l][:] = queue[l][sidx[b]][:]  (queue[l] is L2-hot)
    const int cb = t >> 6;     // 0..3
    const int cc = t & 63;     // float4 index within the 256-float row
    for (int b0 = 0; b0 < 64; b0 += 4) {
        const int b  = b0 + cb;
        const int mi = sidx[b];
        const float4 v = *reinterpret_cast<const float4*>(
            &queue[((size_t)l * M_ + mi) * F_ + cc * 4]);
        *reinterpret_cast<float4*>(&out[((size_t)b * L_ + l) * F_ + cc * 4]) = v;
    }
}

extern "C" void kernel_launch(void* const* d_in, const int* in_sizes, int n_in,
                              void* d_out, int out_size, void* d_ws, size_t ws_size,
                              hipStream_t stream) {
    const float* patch = (const float*)d_in[0];
    const float* queue = (const float*)d_in[1];
    float* out = (float*)d_out;
    mq_fused_kernel<<<dim3(L_), dim3(256), 0, stream>>>(patch, queue, out);
}